// Round 15
// baseline (39.005 us; speedup 1.0000x reference)
//
#include <hip/hip_runtime.h>

// CenterNeighAtt on MI355X. E=512, F=256, R=4.
//
// Exact math simplifications (validated R1-R14, absmax ~5e-4 vs 2.3e-3 threshold):
//  * alpha = softmax_j(sum_i scores[i,j]) is uniform 1/E: sum_i attention[i,j,f]==1,
//    so column sums of scores are constant in j. lin_w/lin_b are dead inputs.
//  * No max-subtraction in softmaxes: logits bounded (~20), exp far below f32 overflow.
//
// Structure lessons (measured):
//  * Cross-grid sync / __threadfence in-dispatch: toxic (R3/R5/R6/R7). Kernel
//    boundaries + plain stores ONLY. Per-dispatch gap ~3us.
//  * Best structure: 3 dispatches, f-split blocks, 512 blk x 1024 thr = 2 blk/CU
//    = 8 waves/SIMD (R13, 37.4us).
//  * Interiors issue-bound; 2 exp passes irreducible (materializing e = 268MB HBM).
//  * clang scalarizes f2 fp32 math (R14 neutral); hand VOP3P op_sel broken (R10).
//  * Rule #20: only tiny fully-unrolled per-thread arrays.
//
// R15 = R13 with RPB 4->8 at constant occupancy (FB 64->32, NT 16->32): halves
// per-element h/g-load + loop overhead; h/g L2 traffic halves too.

typedef float f4 __attribute__((ext_vector_type(4)));

#define EE 512
#define FF 256
#define RRR 4
#define LOG2E 1.44269504088896340736f
#define RPB 8      // rows per block
#define NT 32      // teams
#define CH 16      // chunk length (512/32)
#define FB 32      // f per block

// --- kA: s[i,:] = softmax_j(sum_r adj[r,i,:]); alpha -----------------------
__global__ __launch_bounds__(256) void kA(const float* __restrict__ adj,
                                          float* __restrict__ s,
                                          float* __restrict__ out) {
    const int i = blockIdx.x;
    const int t = threadIdx.x;
    if (i == 0) {   // alpha: softmax of a constant vector = uniform 1/E
        out[EE * FF + t]       = 1.0f / EE;
        out[EE * FF + 256 + t] = 1.0f / EE;
    }
    const float* base = adj + (size_t)i * EE;
    float t0 = 0.f, t1 = 0.f;
#pragma unroll
    for (int r = 0; r < RRR; ++r) {
        t0 += base[(size_t)r * EE * EE + t];
        t1 += base[(size_t)r * EE * EE + t + 256];
    }
    const float e0 = __expf(t0);
    const float e1 = __expf(t1);
    __shared__ float red[256];
    red[t] = e0 + e1;
    __syncthreads();
    for (int off = 128; off > 0; off >>= 1) {
        if (t < off) red[t] += red[t + off];
        __syncthreads();
    }
    const float inv = 1.0f / red[0];
    s[(size_t)i * EE + t]       = e0 * inv;
    s[(size_t)i * EE + t + 256] = e1 * inv;
}

// --- kB: Z[j,f] = sum_i exp2(lrelu(s[i,j]*h[i,f]*h[j,f])*log2e);
//         g[j,f] = h[j,f] * rcp(Z) -----------------------------------------
__global__ __launch_bounds__(1024, 8) void kB(const float* __restrict__ h,
                                              const float* __restrict__ s,
                                              float* __restrict__ g) {
    const int tid  = threadIdx.x;
    const int fl   = tid & (FB - 1);        // 0..31
    const int team = tid >> 5;              // 0..31
    const int j0   = blockIdx.x * RPB;      // 64 row-groups
    const int f    = blockIdx.y * FB + fl;  // 8 f-blocks
    __shared__ __align__(16) float sl[EE * RPB];  // 16 KB: sl[i*8+r] = s[i][j0+r]
    __shared__ float ps[NT * RPB * FB];           // 32 KB
#pragma unroll
    for (int p = 0; p < 4; ++p) {           // stage 4096 floats
        const int idx = tid + p * 1024;
        sl[idx] = s[(size_t)(idx >> 3) * EE + j0 + (idx & 7)];
    }
    __syncthreads();
    float hj[RPB], Z[RPB];
#pragma unroll
    for (int r = 0; r < RPB; ++r) {
        hj[r] = h[(size_t)(j0 + r) * FF + f] * LOG2E;   // fold log2e
        Z[r] = 0.f;
    }
    const float* hp = h + (size_t)(team * CH) * FF + f;
    const f4* spv = (const f4*)(sl + team * CH * RPB);
#pragma unroll 4
    for (int ii = 0; ii < CH; ++ii) {
        const float hif = hp[(size_t)ii * FF];    // 1 load serves 8 rows
        const f4 sa = spv[ii * 2];                // 2 b128 broadcasts / 8 elems
        const f4 sb = spv[ii * 2 + 1];
        const float sv[RPB] = {sa.x, sa.y, sa.z, sa.w, sb.x, sb.y, sb.z, sb.w};
#pragma unroll
        for (int r = 0; r < RPB; ++r) {
            const float y = sv[r] * hj[r] * hif;
            Z[r] += __builtin_amdgcn_exp2f(fmaxf(y, 0.2f * y));  // lrelu folded
        }
    }
#pragma unroll
    for (int r = 0; r < RPB; ++r) ps[(team * RPB + r) * FB + fl] = Z[r];
    __syncthreads();
    if (tid < RPB * FB) {                   // 256 outputs: r = tid>>5, fq = tid&31
        const int r = tid >> 5, fq = tid & (FB - 1);
        float Zt = 0.f;
#pragma unroll
        for (int t = 0; t < NT; ++t) Zt += ps[(t * RPB + r) * FB + fq];
        const size_t o = (size_t)(j0 + r) * FF + blockIdx.y * FB + fq;
        g[o] = h[o] * __builtin_amdgcn_rcpf(Zt);
    }
}

// --- kC: out[i,f] = elu(sum_j g[j,f]*exp2(lrelu(s[i,j]*h[i,f]*h[j,f])*log2e))
__global__ __launch_bounds__(1024, 8) void kC(const float* __restrict__ h,
                                              const float* __restrict__ s,
                                              const float* __restrict__ g,
                                              float* __restrict__ out) {
    const int tid  = threadIdx.x;
    const int fl   = tid & (FB - 1);
    const int team = tid >> 5;
    const int i0   = blockIdx.x * RPB;
    const int f    = blockIdx.y * FB + fl;
    __shared__ __align__(16) float sl[EE * RPB];  // sl[j*8+r] = s[i0+r][j]
    __shared__ float ps[NT * RPB * FB];
#pragma unroll
    for (int p = 0; p < 4; ++p) {
        const int idx = tid + p * 1024;
        sl[idx] = s[(size_t)(i0 + (idx & 7)) * EE + (idx >> 3)];
    }
    __syncthreads();
    float hl[RPB], acc[RPB];
#pragma unroll
    for (int r = 0; r < RPB; ++r) {
        hl[r] = h[(size_t)(i0 + r) * FF + f] * LOG2E;
        acc[r] = 0.f;
    }
    const float* hp = h + (size_t)(team * CH) * FF + f;
    const float* gp = g + (size_t)(team * CH) * FF + f;
    const f4* spv = (const f4*)(sl + team * CH * RPB);
#pragma unroll 4
    for (int jj = 0; jj < CH; ++jj) {
        const float hjf = hp[(size_t)jj * FF];    // 2 loads serve 8 rows
        const float gj  = gp[(size_t)jj * FF];
        const f4 sa = spv[jj * 2];
        const f4 sb = spv[jj * 2 + 1];
        const float sv[RPB] = {sa.x, sa.y, sa.z, sa.w, sb.x, sb.y, sb.z, sb.w};
#pragma unroll
        for (int r = 0; r < RPB; ++r) {
            const float y = sv[r] * hl[r] * hjf;
            acc[r] = fmaf(__builtin_amdgcn_exp2f(fmaxf(y, 0.2f * y)), gj, acc[r]);
        }
    }
#pragma unroll
    for (int r = 0; r < RPB; ++r) ps[(team * RPB + r) * FB + fl] = acc[r];
    __syncthreads();
    if (tid < RPB * FB) {
        const int r = tid >> 5, fq = tid & (FB - 1);
        float a = 0.f;
#pragma unroll
        for (int t = 0; t < NT; ++t) a += ps[(t * RPB + r) * FB + fq];
        out[(size_t)(i0 + r) * FF + blockIdx.y * FB + fq] =
            (a > 0.f) ? a : (__expf(a) - 1.0f);
    }
}

extern "C" void kernel_launch(void* const* d_in, const int* in_sizes, int n_in,
                              void* d_out, int out_size, void* d_ws, size_t ws_size,
                              hipStream_t stream) {
    const float* h   = (const float*)d_in[0];  // [E,F]
    const float* adj = (const float*)d_in[1];  // [R,E,E]
    // lin_w / lin_b mathematically dead (alpha uniform).

    float* s   = (float*)d_ws;                 // 1 MB
    float* g   = s + (size_t)EE * EE;          // 512 KB (total 1.5 MB)
    float* out = (float*)d_out;

    kA<<<EE, 256, 0, stream>>>(adj, s, out);
    kB<<<dim3(EE / RPB, FF / FB), 1024, 0, stream>>>(h, s, g);
    kC<<<dim3(EE / RPB, FF / FB), 1024, 0, stream>>>(h, s, g, out);
}

// Round 16
// 37.493 us; speedup vs baseline: 1.0403x; 1.0403x over previous
//
#include <hip/hip_runtime.h>

// CenterNeighAtt on MI355X. E=512, F=256, R=4.
//
// Exact math simplifications (validated R1-R15, absmax ~5e-4 vs 2.3e-3 threshold):
//  * alpha = softmax_j(sum_i scores[i,j]) is uniform 1/E: sum_i attention[i,j,f]==1,
//    so column sums of scores are constant in j. lin_w/lin_b are dead inputs.
//  * No max-subtraction in softmaxes: logits bounded (~20), exp far below f32 overflow.
//
// Structure lessons (measured):
//  * Cross-grid sync / __threadfence in-dispatch: toxic (R3/R5/R6/R7). Kernel
//    boundaries + plain stores ONLY. Per-dispatch gap ~3us.
//  * Best: 3 dispatches, f-split, 8 waves/SIMD, RPB=4 (R13 37.4us). RPB=8 worse
//    (R15 39.0); f2 packing neutral (R14); traffic not the limiter (R11-R13).
//  * Rule #20: only tiny fully-unrolled per-thread arrays. No VOP3P asm (R10).
//
// R16 = R13 at finer block granularity: 512-thr blocks x 1024 blocks = 4 blk/CU
// x 8 waves = 32 waves/CU (max). Cheaper 8-wave barriers, more independent blocks
// to overlap stage/compute/tail. Per-thread work identical to R13.

typedef float f4 __attribute__((ext_vector_type(4)));

#define EE 512
#define FF 256
#define RRR 4
#define LOG2E 1.44269504088896340736f
#define TPB 512    // threads per block
#define RPB 4      // rows per block
#define NT 16      // teams
#define CH 32      // chunk length (512/16)
#define FB 32      // f per block

// --- kA: s[i,:] = softmax_j(sum_r adj[r,i,:]); alpha -----------------------
__global__ __launch_bounds__(256) void kA(const float* __restrict__ adj,
                                          float* __restrict__ s,
                                          float* __restrict__ out) {
    const int i = blockIdx.x;
    const int t = threadIdx.x;
    if (i == 0) {   // alpha: softmax of a constant vector = uniform 1/E
        out[EE * FF + t]       = 1.0f / EE;
        out[EE * FF + 256 + t] = 1.0f / EE;
    }
    const float* base = adj + (size_t)i * EE;
    float t0 = 0.f, t1 = 0.f;
#pragma unroll
    for (int r = 0; r < RRR; ++r) {
        t0 += base[(size_t)r * EE * EE + t];
        t1 += base[(size_t)r * EE * EE + t + 256];
    }
    const float e0 = __expf(t0);
    const float e1 = __expf(t1);
    __shared__ float red[256];
    red[t] = e0 + e1;
    __syncthreads();
    for (int off = 128; off > 0; off >>= 1) {
        if (t < off) red[t] += red[t + off];
        __syncthreads();
    }
    const float inv = 1.0f / red[0];
    s[(size_t)i * EE + t]       = e0 * inv;
    s[(size_t)i * EE + t + 256] = e1 * inv;
}

// --- kB: Z[j,f] = sum_i exp2(lrelu(s[i,j]*h[i,f]*h[j,f])*log2e);
//         g[j,f] = h[j,f] * rcp(Z) -----------------------------------------
__global__ __launch_bounds__(TPB, 8) void kB(const float* __restrict__ h,
                                             const float* __restrict__ s,
                                             float* __restrict__ g) {
    const int tid  = threadIdx.x;
    const int fl   = tid & (FB - 1);        // 0..31
    const int team = tid >> 5;              // 0..15
    const int j0   = blockIdx.x * RPB;      // 128 row-groups
    const int f    = blockIdx.y * FB + fl;  // 8 f-blocks
    __shared__ __align__(16) float sl[EE * RPB];  // 8 KB: sl[i*4+r] = s[i][j0+r]
    __shared__ float ps[NT * RPB * FB];           // 8 KB
#pragma unroll
    for (int p = 0; p < 4; ++p) {           // stage 2048 floats
        const int idx = tid + p * TPB;
        sl[idx] = s[(size_t)(idx >> 2) * EE + j0 + (idx & 3)];
    }
    __syncthreads();
    float hj0 = h[(size_t)j0 * FF + f] * LOG2E;   // fold log2e
    float hj1 = h[(size_t)(j0 + 1) * FF + f] * LOG2E;
    float hj2 = h[(size_t)(j0 + 2) * FF + f] * LOG2E;
    float hj3 = h[(size_t)(j0 + 3) * FF + f] * LOG2E;
    float Z0 = 0.f, Z1 = 0.f, Z2 = 0.f, Z3 = 0.f;
    const float* hp = h + (size_t)(team * CH) * FF + f;
    const f4* spv = (const f4*)(sl + team * CH * RPB);
#pragma unroll 4
    for (int ii = 0; ii < CH; ++ii) {
        const float hif = hp[(size_t)ii * FF];    // 1 load serves 4 rows
        const f4 sv = spv[ii];                    // ds_read_b128 broadcast
        const float y0 = sv.x * hj0 * hif;
        const float y1 = sv.y * hj1 * hif;
        const float y2 = sv.z * hj2 * hif;
        const float y3 = sv.w * hj3 * hif;
        Z0 += __builtin_amdgcn_exp2f(fmaxf(y0, 0.2f * y0));   // lrelu folded
        Z1 += __builtin_amdgcn_exp2f(fmaxf(y1, 0.2f * y1));
        Z2 += __builtin_amdgcn_exp2f(fmaxf(y2, 0.2f * y2));
        Z3 += __builtin_amdgcn_exp2f(fmaxf(y3, 0.2f * y3));
    }
    ps[(team * RPB + 0) * FB + fl] = Z0;
    ps[(team * RPB + 1) * FB + fl] = Z1;
    ps[(team * RPB + 2) * FB + fl] = Z2;
    ps[(team * RPB + 3) * FB + fl] = Z3;
    __syncthreads();
    if (tid < RPB * FB) {                    // 128 outputs: r = tid>>5, fq = tid&31
        const int r = tid >> 5, fq = tid & (FB - 1);
        float Zt = 0.f;
#pragma unroll
        for (int t = 0; t < NT; ++t) Zt += ps[(t * RPB + r) * FB + fq];
        const size_t o = (size_t)(j0 + r) * FF + blockIdx.y * FB + fq;
        g[o] = h[o] * __builtin_amdgcn_rcpf(Zt);
    }
}

// --- kC: out[i,f] = elu(sum_j g[j,f]*exp2(lrelu(s[i,j]*h[i,f]*h[j,f])*log2e))
__global__ __launch_bounds__(TPB, 8) void kC(const float* __restrict__ h,
                                             const float* __restrict__ s,
                                             const float* __restrict__ g,
                                             float* __restrict__ out) {
    const int tid  = threadIdx.x;
    const int fl   = tid & (FB - 1);
    const int team = tid >> 5;
    const int i0   = blockIdx.x * RPB;
    const int f    = blockIdx.y * FB + fl;
    __shared__ __align__(16) float sl[EE * RPB];  // sl[j*4+r] = s[i0+r][j]
    __shared__ float ps[NT * RPB * FB];
#pragma unroll
    for (int p = 0; p < 4; ++p) {
        const int idx = tid + p * TPB;
        sl[idx] = s[(size_t)(i0 + (idx & 3)) * EE + (idx >> 2)];
    }
    __syncthreads();
    float hl0 = h[(size_t)i0 * FF + f] * LOG2E;
    float hl1 = h[(size_t)(i0 + 1) * FF + f] * LOG2E;
    float hl2 = h[(size_t)(i0 + 2) * FF + f] * LOG2E;
    float hl3 = h[(size_t)(i0 + 3) * FF + f] * LOG2E;
    float a0 = 0.f, a1 = 0.f, a2 = 0.f, a3 = 0.f;
    const float* hp = h + (size_t)(team * CH) * FF + f;
    const float* gp = g + (size_t)(team * CH) * FF + f;
    const f4* spv = (const f4*)(sl + team * CH * RPB);
#pragma unroll 4
    for (int jj = 0; jj < CH; ++jj) {
        const float hjf = hp[(size_t)jj * FF];    // 2 loads serve 4 rows
        const float gj  = gp[(size_t)jj * FF];
        const f4 sv = spv[jj];                    // ds_read_b128 broadcast
        const float y0 = sv.x * hl0 * hjf;
        const float y1 = sv.y * hl1 * hjf;
        const float y2 = sv.z * hl2 * hjf;
        const float y3 = sv.w * hl3 * hjf;
        a0 = fmaf(__builtin_amdgcn_exp2f(fmaxf(y0, 0.2f * y0)), gj, a0);
        a1 = fmaf(__builtin_amdgcn_exp2f(fmaxf(y1, 0.2f * y1)), gj, a1);
        a2 = fmaf(__builtin_amdgcn_exp2f(fmaxf(y2, 0.2f * y2)), gj, a2);
        a3 = fmaf(__builtin_amdgcn_exp2f(fmaxf(y3, 0.2f * y3)), gj, a3);
    }
    ps[(team * RPB + 0) * FB + fl] = a0;
    ps[(team * RPB + 1) * FB + fl] = a1;
    ps[(team * RPB + 2) * FB + fl] = a2;
    ps[(team * RPB + 3) * FB + fl] = a3;
    __syncthreads();
    if (tid < RPB * FB) {
        const int r = tid >> 5, fq = tid & (FB - 1);
        float a = 0.f;
#pragma unroll
        for (int t = 0; t < NT; ++t) a += ps[(t * RPB + r) * FB + fq];
        out[(size_t)(i0 + r) * FF + blockIdx.y * FB + fq] =
            (a > 0.f) ? a : (__expf(a) - 1.0f);
    }
}

extern "C" void kernel_launch(void* const* d_in, const int* in_sizes, int n_in,
                              void* d_out, int out_size, void* d_ws, size_t ws_size,
                              hipStream_t stream) {
    const float* h   = (const float*)d_in[0];  // [E,F]
    const float* adj = (const float*)d_in[1];  // [R,E,E]
    // lin_w / lin_b mathematically dead (alpha uniform).

    float* s   = (float*)d_ws;                 // 1 MB
    float* g   = s + (size_t)EE * EE;          // 512 KB (total 1.5 MB)
    float* out = (float*)d_out;

    kA<<<EE, 256, 0, stream>>>(adj, s, out);
    kB<<<dim3(EE / RPB, FF / FB), TPB, 0, stream>>>(h, s, g);
    kC<<<dim3(EE / RPB, FF / FB), TPB, 0, stream>>>(h, s, g, out);
}